// Round 1
// baseline (126337.073 us; speedup 1.0000x reference)
//
#include <hip/hip_runtime.h>
#include <math.h>

typedef unsigned long long u64;

#define NN 4096
#define MM 128
#define CCI 4095

// scratch layout inside d_out (bytes)
#define OFF_PCT 0            // double[4096*128] = 4 MB
#define OFF_RM  4194304      // u64[4096*2] row bitmasks, 64 KB
#define OFF_CM  4259840      // u64[128*64] col bitmasks, 64 KB
#define OFF_STS 4325376      // int[128*128], 64 KB
#define OFF_ST1 4390912      // int[128]
#define OFF_D   4456448      // signed char[4096*128], 512 KB
#define TAILB   67043328     // 64MB - 64KB : final resting place of row masks

// ---------------- init: bitpack S ----------------
__global__ void k_pack_rows(const float* __restrict__ S, u64* __restrict__ RM) {
  int lane = threadIdx.x & 63;
  int w = blockIdx.x * 4 + (threadIdx.x >> 6);
  for (int rr = 0; rr < 16; ++rr) {
    int row = w * 16 + rr;
    u64 m0 = __ballot(S[(size_t)row * MM + lane] > 0.5f);
    u64 m1 = __ballot(S[(size_t)row * MM + 64 + lane] > 0.5f);
    if (lane == 0) { RM[row * 2] = m0; RM[row * 2 + 1] = m1; }
  }
}

__global__ void k_pack_cols(const float* __restrict__ S, u64* __restrict__ CM) {
  int lane = threadIdx.x & 63;
  int w = blockIdx.x * 4 + (threadIdx.x >> 6);
  for (int k = 0; k < 64; ++k) {
    int pair = w * 64 + k;
    int j = pair >> 6, wd = pair & 63;
    u64 m = __ballot(S[((size_t)wd * 64 + lane) * MM + j] > 0.5f);
    if (lane == 0) CM[j * 64 + wd] = m;
  }
}

__global__ void k_init_sts(const u64* __restrict__ CM, int* __restrict__ StSg,
                           int* __restrict__ St1g) {
  int id = blockIdx.x * 256 + threadIdx.x;
  int a = id >> 7, b = id & 127;
  int s = 0;
  for (int w = 0; w < 64; ++w) s += __popcll(CM[a * 64 + w] & CM[b * 64 + w]);
  StSg[a * 128 + b] = s;
  if (a == b) St1g[a] = s;
}

// ---------------- P = S0^T K  (f64 accum), PCT[col][j] ----------------
__global__ void k_pgemm(const float* __restrict__ K, const float* __restrict__ S,
                        double* __restrict__ PCT) {
  __shared__ float Slds[64 * 128];
  __shared__ float Klds[64 * 16];
  int tid = threadIdx.x;
  int col0 = blockIdx.x * 16;
  int c = tid & 15, jg = tid >> 4;
  int j0 = jg * 8;
  double acc[8];
#pragma unroll
  for (int q = 0; q < 8; ++q) acc[q] = 0.0;
  for (int rb = 0; rb < NN; rb += 64) {
    for (int k = 0; k < 32; ++k)
      Slds[k * 256 + tid] = S[(size_t)rb * MM + k * 256 + tid];
    for (int k = 0; k < 4; ++k) {
      int idx = k * 256 + tid;
      int rr = idx >> 4, cc = idx & 15;
      Klds[idx] = K[(size_t)(rb + rr) * NN + col0 + cc];
    }
    __syncthreads();
    for (int rr = 0; rr < 64; ++rr) {
      double kv = (double)Klds[rr * 16 + c];
#pragma unroll
      for (int q = 0; q < 8; ++q)
        acc[q] += (double)Slds[rr * 128 + j0 + q] * kv;
    }
    __syncthreads();
  }
#pragma unroll
  for (int q = 0; q < 8; ++q)
    PCT[(size_t)(col0 + c) * MM + j0 + q] = acc[q];
}

// ---------------- per-block correction GEMM: PCT[col][j] += sum_t d[t][j]*K[p_t][col]
__global__ void k_cgemm(const float* __restrict__ K, const int* __restrict__ perm,
                        const signed char* __restrict__ Dg, double* __restrict__ PCT,
                        int blk) {
  __shared__ float sDD[128 * 128];
  __shared__ float sDk[128 * 16];
  int tid = threadIdx.x;
  int col0 = blockIdx.x * 16;
  int base = blk * 128;
  for (int k = 0; k < 64; ++k)
    sDD[k * 256 + tid] = (float)Dg[(size_t)base * MM + k * 256 + tid];
  if (tid < 128) {
    int pj = perm[base + tid];
    for (int cc = 0; cc < 16; ++cc)
      sDk[tid * 16 + cc] = K[(size_t)pj * NN + col0 + cc];
  }
  __syncthreads();
  int c = tid & 15, jg = tid >> 4;
  int j0 = jg * 8;
  double acc[8];
#pragma unroll
  for (int q = 0; q < 8; ++q) acc[q] = 0.0;
  for (int tp = 0; tp < 128; ++tp) {
    double kv = (double)sDk[tp * 16 + c];
#pragma unroll
    for (int q = 0; q < 8; ++q)
      acc[q] += (double)sDD[tp * 128 + j0 + q] * kv;
  }
#pragma unroll
  for (int q = 0; q < 8; ++q) {
    size_t o = (size_t)(col0 + c) * MM + j0 + q;
    PCT[o] += acc[q];
  }
}

// ---------------- the sequential Gibbs block kernel ----------------
__global__ __launch_bounds__(1024) void k_seq(const float* __restrict__ K,
                                              const float* __restrict__ Uin,
                                              const int* __restrict__ perm,
                                              char* scratch, int blk) {
  __shared__ int sStS[128 * 128];            // 64 KB
  __shared__ signed char sR[128 * 128];      // 16 KB
  __shared__ signed char sD[128 * 128];      // 16 KB
  __shared__ double sScr[4][512];            // 16 KB
  __shared__ double sPC[128], sQ[128], sP1f[128], sRRf[128], sCorr[128];
  __shared__ float sKcol[128], sU[128];
  __shared__ int sSt1[128], sRvec[128];
  __shared__ u64 sMaskS[2], sMaskN[2];

  int tid = threadIdx.x;
  int* StSg = (int*)(scratch + OFF_STS);
  int* St1g = (int*)(scratch + OFF_ST1);
  double* PCT = (double*)(scratch + OFF_PCT);
  u64* RMg = (u64*)(scratch + OFF_RM);
  signed char* Dg = (signed char*)(scratch + OFF_D);
  int base = blk * 128;

  for (int k = 0; k < 16; ++k) sStS[k * 1024 + tid] = StSg[k * 1024 + tid];
  if (tid < 128) sSt1[tid] = St1g[tid];
  __syncthreads();

  for (int t = 0; t < 128; ++t) {
    int row = perm[base + t];
    // ---- P0: stage per-row data
    if (tid < 128) {
      int pj = perm[base + tid];
      sKcol[tid] = K[(size_t)pj * NN + row];
    } else if (tid < 256) {
      int j = tid - 128;
      sPC[j] = PCT[(size_t)row * MM + j];
    } else if (tid < 384) {
      int j = tid - 256;
      sU[j] = Uin[(size_t)(base + t) * MM + j];
    } else if (tid < 512) {
      sRvec[tid - 384] = 0;
    } else if (tid == 512) {
      sMaskS[0] = RMg[(size_t)row * 2];
      sMaskS[1] = RMg[(size_t)row * 2 + 1];
    }
    __syncthreads();
    // ---- P0b: downdate StS/St1 by outer(s,s), s
    {
      u64 m0 = sMaskS[0], m1 = sMaskS[1];
      int b = tid & 127, g = tid >> 7;
      int sbB = (int)(((b < 64 ? m0 : m1) >> (b & 63)) & 1);
      if (sbB) {
        for (int k = 0; k < 16; ++k) {
          int a = g * 16 + k;
          int sbA = (int)(((a < 64 ? m0 : m1) >> (a & 63)) & 1);
          sStS[a * 128 + b] -= sbA;
        }
      }
      if (tid < 128) sSt1[tid] -= (int)(((tid < 64 ? m0 : m1) >> (tid & 63)) & 1);
    }
    __syncthreads();
    // ---- P1: exact integer pass for R and r
    {
      int b = tid & 127, g = tid >> 7;
      int q = sSt1[b];
      int racc = 0;
      for (int k = 0; k < 16; ++k) {
        int a = g * 16 + k;
        int p = sSt1[a];
        int x = sStS[a * 128 + b];
        int y = x + x;
        int pq = p + q;
        int T2 = pq + q - CCI;  // = p + 2q - c
        int T3 = pq + p - CCI;  // = 2p + q - c
        int b1 = (y < q) & (y < p) & (pq < CCI);
        int b2 = (q < y) & (q < p) & (y > T2);
        int b3 = (p < y) & (p < q) & (y > T3);
        int b4 = (CCI < pq) & (y < T2) & (y < T3);
        sR[a * 128 + b] = (signed char)(b1 - b2 - b3 + b4);
        racc += b2 - b4;
      }
      atomicAdd(&sRvec[b], racc);
    }
    __syncthreads();
    // ---- P2: Q = StS@St1, P1 = StS@s, RR = R@s, corr (in-block Sk corrections)
    if (tid < 512) {
      int j = tid & 127, g = tid >> 7;
      u64 m0 = sMaskS[0], m1 = sMaskS[1];
      double aQ = 0.0, aC = 0.0;
      int aP = 0, aR = 0;
      for (int k = 0; k < 32; ++k) {
        int bb = g * 32 + k;
        int x = sStS[bb * 128 + j];  // symmetric: StS[j][bb]
        aQ += (double)x * (double)sSt1[bb];
        int sbit = (int)(((bb < 64 ? m0 : m1) >> (bb & 63)) & 1);
        aP += x * sbit;
        aR += (int)sR[bb * 128 + j] * sbit;
        if (bb < t) aC += (double)sD[bb * 128 + j] * (double)sKcol[bb];
      }
      sScr[0][g * 128 + j] = aQ;
      sScr[1][g * 128 + j] = (double)aP;
      sScr[2][g * 128 + j] = (double)aR;
      sScr[3][g * 128 + j] = aC;
    }
    __syncthreads();
    if (tid < 128) {
      double a0 = 0, a1 = 0, a2 = 0, a3 = 0;
      for (int g = 0; g < 4; ++g) {
        a0 += sScr[0][g * 128 + tid];
        a1 += sScr[1][g * 128 + tid];
        a2 += sScr[2][g * 128 + tid];
        a3 += sScr[3][g * 128 + tid];
      }
      sQ[tid] = a0; sP1f[tid] = a1; sRRf[tid] = a2; sCorr[tid] = a3;
    }
    __syncthreads();
    // ---- P3 + P4: wave0 does row init and the sequential element loop
    if (tid < 64) {
      const int l = tid;
      int st0 = sSt1[l], st1 = sSt1[l + 64];
      double st0d = (double)st0, st1d = (double)st1;
      int rv0 = sRvec[l], rv1 = sRvec[l + 64];
      double Q0 = sQ[l], Q1 = sQ[l + 64];
      double P1d0 = sP1f[l], P1d1 = sP1f[l + 64];
      double RRd0 = sRRf[l], RRd1 = sRRf[l + 64];
      u64 um0 = sMaskS[0], um1 = sMaskS[1];
      int sb0 = (int)((um0 >> l) & 1), sb1 = (int)((um1 >> l) & 1);
      int nb0 = sb0, nb1 = sb1;
      double k0d = (double)sKcol[t];
      double Sk0 = sPC[l] + sCorr[l] - (sb0 ? k0d : 0.0);
      double Sk1 = sPC[l + 64] + sCorr[l + 64] - (sb1 ? k0d : 0.0);
      const double c = 4095.0;
      const double tt = 4095.0 / 4096.0;
      double s_0 = st0d / c, s_1 = st1d / c;
      double uv0 = 2.0 * s_0 - 1.0, uv1 = 2.0 * s_1 - 1.0;
      double ssc0 = s_0 * (1.0 - s_0), ssc1 = s_1 * (1.0 - s_1);
      double Jii0 = 2.0 * c * ssc0 + tt * uv0 * uv0;
      double Jii1 = 2.0 * c * ssc1 + tt * uv1 * uv1;
      double sscS = ssc0 + ssc1;
      double SSv = st0d * st0d + st1d * st1d;
      double S1v = st0d + st1d;
      double SNv = st0d * (double)nb0 + st1d * (double)nb1;
      double Nnv = (double)(nb0 + nb1);
#pragma unroll
      for (int o = 1; o < 64; o <<= 1) {
        sscS += __shfl_xor(sscS, o);
        SSv += __shfl_xor(SSv, o);
        S1v += __shfl_xor(S1v, o);
        SNv += __shfl_xor(SNv, o);
        Nnv += __shfl_xor(Nnv, o);
      }
      double h0 = tt * (sscS - k0d) * uv0 + 2.0 * Sk0 - 0.01 * (double)rv0;
      double h1 = tt * (sscS - k0d) * uv1 + 2.0 * Sk1 - 0.01 * (double)rv1;
      double c2 = c * c;
      double SSc2 = SSv / c2, S1sc = S1v / c;
      // curr_j = C0[j] + C1[j]*SN + C2[j]*Nn - 4*P1[j] - 0.02*RR[j] + n_j*JT[j]
      double C00 = 2.0 * h0 - Jii0 + 4.0 * Q0 / c + 4.0 * SSc2 * (tt * uv0 - st0d) - 2.0 * tt * uv0 * S1sc;
      double C01 = 2.0 * h1 - Jii1 + 4.0 * Q1 / c + 4.0 * SSc2 * (tt * uv1 - st1d) - 2.0 * tt * uv1 * S1sc;
      double C10 = (4.0 / c) * (st0d - tt * uv0), C11 = (4.0 / c) * (st1d - tt * uv1);
      double C20 = 2.0 * tt * uv0, C21 = 2.0 * tt * uv1;
      double JT0 = 2.0 * Jii0, JT1 = 2.0 * Jii1;
      float uu0 = sU[l], uu1 = sU[l + 64];
      double L0 = (uu0 <= 0.0f) ? -1e300 : log((double)uu0 / (1.0 - (double)uu0));
      double L1 = (uu1 <= 0.0f) ? -1e300 : log((double)uu1 / (1.0 - (double)uu1));
      double SNd = SNv, Nnd = Nnv;
      int jmin = 0;
      while (jmin < 128) {
        double cur0 = C00 + C10 * SNd + C20 * Nnd - 4.0 * P1d0 - 0.02 * RRd0 + (nb0 ? JT0 : 0.0);
        double cur1 = C01 + C11 * SNd + C21 * Nnd - 4.0 * P1d1 - 0.02 * RRd1 + (nb1 ? JT1 : 0.0);
        int d0 = (cur0 < -100.0) ? 0 : ((cur0 > 100.0) ? 1 : (L0 < cur0 ? 1 : 0));
        int d1 = (cur1 < -100.0) ? 0 : ((cur1 > 100.0) ? 1 : (L1 < cur1 ? 1 : 0));
        u64 f0 = __ballot(d0 != nb0);
        u64 f1 = __ballot(d1 != nb1);
        if (jmin < 64) {
          f0 &= (~0ull) << jmin;
        } else {
          f0 = 0;
          f1 &= (~0ull) << (jmin - 64);
        }
        if (!(f0 | f1)) break;
        int jj = f0 ? __builtin_ctzll(f0) : 64 + __builtin_ctzll(f1);
        int slot = jj >> 6, ll = jj & 63;
        int nbjj; double stjj;
        if (slot == 0) { nbjj = __shfl(nb0, ll); stjj = __shfl(st0d, ll); }
        else           { nbjj = __shfl(nb1, ll); stjj = __shfl(st1d, ll); }
        double dsd = nbjj ? -1.0 : 1.0;
        SNd += dsd * stjj;
        Nnd += dsd;
        P1d0 += dsd * (double)sStS[jj * 128 + l];
        P1d1 += dsd * (double)sStS[jj * 128 + 64 + l];
        RRd0 += dsd * (double)sR[jj * 128 + l];
        RRd1 += dsd * (double)sR[jj * 128 + 64 + l];
        if (slot == 0) { if (l == ll) nb0 ^= 1; }
        else           { if (l == ll) nb1 ^= 1; }
        jmin = jj + 1;
      }
      // commit row results
      sSt1[l] = st0 + nb0;
      sSt1[l + 64] = st1 + nb1;
      signed char dd0 = (signed char)(nb0 - sb0);
      signed char dd1 = (signed char)(nb1 - sb1);
      sD[t * 128 + l] = dd0;
      sD[t * 128 + 64 + l] = dd1;
      Dg[(size_t)(base + t) * MM + l] = dd0;
      Dg[(size_t)(base + t) * MM + 64 + l] = dd1;
      u64 nm0 = __ballot(nb0 != 0), nm1 = __ballot(nb1 != 0);
      if (l == 0) {
        sMaskN[0] = nm0; sMaskN[1] = nm1;
        RMg[(size_t)row * 2] = nm0;
        RMg[(size_t)row * 2 + 1] = nm1;
      }
    }
    __syncthreads();
    // ---- P5: update StS += outer(news,news)
    {
      u64 m0 = sMaskN[0], m1 = sMaskN[1];
      int b = tid & 127, g = tid >> 7;
      int nbB = (int)(((b < 64 ? m0 : m1) >> (b & 63)) & 1);
      if (nbB) {
        for (int k = 0; k < 16; ++k) {
          int a = g * 16 + k;
          int nbA = (int)(((a < 64 ? m0 : m1) >> (a & 63)) & 1);
          sStS[a * 128 + b] += nbA;
        }
      }
    }
    __syncthreads();
  }
  for (int k = 0; k < 16; ++k) StSg[k * 1024 + tid] = sStS[k * 1024 + tid];
  if (tid < 128) St1g[tid] = sSt1[tid];
}

// ---------------- output: out = Snew @ Snew^T via popcount ----------------
__global__ void k_copy_tail(char* scratch, float* out) {
  u64* TM = (u64*)((char*)out + TAILB);
  const u64* RM = (const u64*)(scratch + OFF_RM);
  int tid = threadIdx.x;
  for (int k = 0; k < 16; ++k) TM[k * 512 + tid] = RM[k * 512 + tid];
}

__global__ void k_out_main(float* __restrict__ out) {
  const u64* TM = (const u64*)((const char*)out + TAILB);
  int a = blockIdx.x;  // 0..4091
  u64 a0 = TM[a * 2], a1 = TM[a * 2 + 1];
  int tid = threadIdx.x;
  for (int k = 0; k < 16; ++k) {
    int b = k * 256 + tid;
    u64 b0 = TM[b * 2], b1 = TM[b * 2 + 1];
    out[(size_t)a * NN + b] = (float)(__popcll(a0 & b0) + __popcll(a1 & b1));
  }
}

__global__ void k_out_tail(float* __restrict__ out) {
  __shared__ u64 sM[8192];
  const u64* TM = (const u64*)((const char*)out + TAILB);
  int tid = threadIdx.x;
  for (int k = 0; k < 8; ++k) sM[k * 1024 + tid] = TM[k * 1024 + tid];
  __syncthreads();
  for (int k = 0; k < 16; ++k) {
    int e = k * 1024 + tid;
    int a = 4092 + (e >> 12), b = e & 4095;
    out[(size_t)a * NN + b] =
        (float)(__popcll(sM[a * 2] & sM[b * 2]) + __popcll(sM[a * 2 + 1] & sM[b * 2 + 1]));
  }
}

extern "C" void kernel_launch(void* const* d_in, const int* in_sizes, int n_in,
                              void* d_out, int out_size, void* d_ws, size_t ws_size,
                              hipStream_t stream) {
  (void)in_sizes; (void)n_in; (void)out_size; (void)d_ws; (void)ws_size;
  const float* K = (const float*)d_in[0];
  const float* S = (const float*)d_in[1];
  const float* U = (const float*)d_in[2];
  const int* perm = (const int*)d_in[3];
  char* scratch = (char*)d_out;
  float* out = (float*)d_out;
  u64* RM = (u64*)(scratch + OFF_RM);
  u64* CM = (u64*)(scratch + OFF_CM);
  int* StSg = (int*)(scratch + OFF_STS);
  int* St1g = (int*)(scratch + OFF_ST1);
  double* PCT = (double*)(scratch + OFF_PCT);
  signed char* Dg = (signed char*)(scratch + OFF_D);

  hipLaunchKernelGGL(k_pack_rows, dim3(64), dim3(256), 0, stream, S, RM);
  hipLaunchKernelGGL(k_pack_cols, dim3(32), dim3(256), 0, stream, S, CM);
  hipLaunchKernelGGL(k_init_sts, dim3(64), dim3(256), 0, stream, CM, StSg, St1g);
  hipLaunchKernelGGL(k_pgemm, dim3(256), dim3(256), 0, stream, K, S, PCT);
  for (int b = 0; b < 32; ++b) {
    hipLaunchKernelGGL(k_seq, dim3(1), dim3(1024), 0, stream, K, U, perm, scratch, b);
    if (b < 31)
      hipLaunchKernelGGL(k_cgemm, dim3(256), dim3(256), 0, stream, K, perm, Dg, PCT, b);
  }
  hipLaunchKernelGGL(k_copy_tail, dim3(1), dim3(512), 0, stream, scratch, out);
  hipLaunchKernelGGL(k_out_main, dim3(4092), dim3(256), 0, stream, out);
  hipLaunchKernelGGL(k_out_tail, dim3(1), dim3(1024), 0, stream, out);
}

// Round 2
// 95969.330 us; speedup vs baseline: 1.3164x; 1.3164x over previous
//
#include <hip/hip_runtime.h>
#include <math.h>

typedef unsigned long long u64;

#define NN 4096
#define MM 128
#define PAD 132

// scratch layout inside d_out (bytes)
#define OFF_PCT 0            // double[4096*128] = 4 MB
#define OFF_RM  4194304      // u64[4096*2] row bitmasks, 64 KB
#define OFF_CM  4259840      // u64[128*64] col bitmasks, 64 KB
#define OFF_STS 4325376      // int[128*128], 64 KB
#define OFF_ST1 4390912      // int[128]
#define OFF_D   4456448      // signed char[4096*128], 512 KB
#define TAILB   67043328     // 64MB - 64KB : final resting place of row masks

// ---------------- init: bitpack S ----------------
__global__ void k_pack_rows(const float* __restrict__ S, u64* __restrict__ RM) {
  int lane = threadIdx.x & 63;
  int w = blockIdx.x * 4 + (threadIdx.x >> 6);
  for (int rr = 0; rr < 16; ++rr) {
    int row = w * 16 + rr;
    u64 m0 = __ballot(S[(size_t)row * MM + lane] > 0.5f);
    u64 m1 = __ballot(S[(size_t)row * MM + 64 + lane] > 0.5f);
    if (lane == 0) { RM[row * 2] = m0; RM[row * 2 + 1] = m1; }
  }
}

__global__ void k_pack_cols(const float* __restrict__ S, u64* __restrict__ CM) {
  int lane = threadIdx.x & 63;
  int w = blockIdx.x * 4 + (threadIdx.x >> 6);
  for (int k = 0; k < 64; ++k) {
    int pair = w * 64 + k;
    int j = pair >> 6, wd = pair & 63;
    u64 m = __ballot(S[((size_t)wd * 64 + lane) * MM + j] > 0.5f);
    if (lane == 0) CM[j * 64 + wd] = m;
  }
}

__global__ void k_init_sts(const u64* __restrict__ CM, int* __restrict__ StSg,
                           int* __restrict__ St1g) {
  int id = blockIdx.x * 256 + threadIdx.x;
  int a = id >> 7, b = id & 127;
  int s = 0;
  for (int w = 0; w < 64; ++w) s += __popcll(CM[a * 64 + w] & CM[b * 64 + w]);
  StSg[a * 128 + b] = s;
  if (a == b) St1g[a] = s;
}

// ---------------- P = S0^T K  (f64 accum), PCT[col][j] ----------------
__global__ void k_pgemm(const float* __restrict__ K, const float* __restrict__ S,
                        double* __restrict__ PCT) {
  __shared__ float Slds[64 * 128];
  __shared__ float Klds[64 * 16];
  int tid = threadIdx.x;
  int col0 = blockIdx.x * 16;
  int c = tid & 15, jg = tid >> 4;
  int j0 = jg * 8;
  double acc[8];
#pragma unroll
  for (int q = 0; q < 8; ++q) acc[q] = 0.0;
  for (int rb = 0; rb < NN; rb += 64) {
    for (int k = 0; k < 32; ++k)
      Slds[k * 256 + tid] = S[(size_t)rb * MM + k * 256 + tid];
    for (int k = 0; k < 4; ++k) {
      int idx = k * 256 + tid;
      int rr = idx >> 4, cc = idx & 15;
      Klds[idx] = K[(size_t)(rb + rr) * NN + col0 + cc];
    }
    __syncthreads();
    for (int rr = 0; rr < 64; ++rr) {
      double kv = (double)Klds[rr * 16 + c];
#pragma unroll
      for (int q = 0; q < 8; ++q)
        acc[q] += (double)Slds[rr * 128 + j0 + q] * kv;
    }
    __syncthreads();
  }
#pragma unroll
  for (int q = 0; q < 8; ++q)
    PCT[(size_t)(col0 + c) * MM + j0 + q] = acc[q];
}

// ---------------- per-block correction GEMM: PCT[col][j] += sum_t d[t][j]*K[p_t][col]
__global__ void k_cgemm(const float* __restrict__ K, const int* __restrict__ perm,
                        const signed char* __restrict__ Dg, double* __restrict__ PCT,
                        int blk) {
  __shared__ float sDD[128 * 128];
  __shared__ float sDk[128 * 16];
  int tid = threadIdx.x;
  int col0 = blockIdx.x * 16;
  int base = blk * 128;
  for (int k = 0; k < 64; ++k)
    sDD[k * 256 + tid] = (float)Dg[(size_t)base * MM + k * 256 + tid];
  if (tid < 128) {
    int pj = perm[base + tid];
    for (int cc = 0; cc < 16; ++cc)
      sDk[tid * 16 + cc] = K[(size_t)pj * NN + col0 + cc];
  }
  __syncthreads();
  int c = tid & 15, jg = tid >> 4;
  int j0 = jg * 8;
  double acc[8];
#pragma unroll
  for (int q = 0; q < 8; ++q) acc[q] = 0.0;
  for (int tp = 0; tp < 128; ++tp) {
    double kv = (double)sDk[tp * 16 + c];
#pragma unroll
    for (int q = 0; q < 8; ++q)
      acc[q] += (double)sDD[tp * 128 + j0 + q] * kv;
  }
#pragma unroll
  for (int q = 0; q < 8; ++q) {
    size_t o = (size_t)(col0 + c) * MM + j0 + q;
    PCT[o] += acc[q];
  }
}

// ---------------- the sequential Gibbs block kernel ----------------
__global__ __launch_bounds__(1024) void k_seq(const float* __restrict__ Kg,
                                              const float* __restrict__ Uin,
                                              const int* __restrict__ perm,
                                              char* scratch, int blk) {
  __shared__ int sStS[128 * PAD];            // 67584 B, symmetric, pad 132
  __shared__ signed char sDT[128 * PAD];     // D transposed: sDT[j*132 + t]
  __shared__ int rP1[8 * 128], rRR[8 * 128], rr_[8 * 128], rQ[8 * 128];
  __shared__ double rC[8 * 128];
  __shared__ double sPC[128], sQd[128], sCorr[128];
  __shared__ int sP1[128], sRRi[128], sRv[128], sSt1[128], sPerm[128];
  __shared__ float sKc[128], sU[128];
  __shared__ u64 sBM[128][2];
  __shared__ u64 sPrevN[2], sCurS[2];

  const int tid = threadIdx.x;
  int* StSg = (int*)(scratch + OFF_STS);
  int* St1g = (int*)(scratch + OFF_ST1);
  double* PCT = (double*)(scratch + OFF_PCT);
  u64* RMg = (u64*)(scratch + OFF_RM);
  signed char* Dg = (signed char*)(scratch + OFF_D);
  const int base = blk * 128;

  // ---- prologue
  for (int k = 0; k < 16; ++k) {
    int idx = k * 1024 + tid;
    int a = idx >> 7, b = idx & 127;
    sStS[a * PAD + b] = StSg[idx];
  }
  for (int idx = tid; idx < 128 * PAD / 4; idx += 1024) ((int*)sDT)[idx] = 0;
  int pjReg = 0;
  float regK = 0.f, regU = 0.f;
  double regPC = 0.0;
  if (tid < 128) {
    int pj = perm[base + tid];
    pjReg = pj;
    sPerm[tid] = pj;
    sSt1[tid] = St1g[tid];
    sBM[tid][0] = RMg[(size_t)pj * 2];
    sBM[tid][1] = RMg[(size_t)pj * 2 + 1];
    int r0 = perm[base];
    regK = Kg[(size_t)pj * NN + r0];
    regPC = PCT[(size_t)r0 * MM + tid];
    regU = Uin[(size_t)base * MM + tid];
  }
  if (tid == 0) { sPrevN[0] = 0; sPrevN[1] = 0; }
  __syncthreads();

  for (int t = 0; t < 128; ++t) {
    // ---- PRE: commit staged regs, update St1 (+news_{t-1} - s_t)
    if (tid < 128) {
      sKc[tid] = regK;
      sPC[tid] = regPC;
      sU[tid] = regU;
      u64 ow = sBM[t][tid >> 6];
      int ob = (int)((ow >> (tid & 63)) & 1);
      u64 pw = (tid < 64) ? sPrevN[0] : sPrevN[1];
      int pb = (int)((pw >> (tid & 63)) & 1);
      sSt1[tid] += pb - ob;
      if (tid == 0) { sCurS[0] = sBM[t][0]; sCurS[1] = sBM[t][1]; }
    }
    __syncthreads();

    // ---- A: fused delta-apply + R/Q/P1/RR/r/corr streaming pass
    {
      // prefetch next row's staging into registers (consumed 3 barriers later)
      if (t < 127 && tid < 128) {
        int rn = sPerm[t + 1];
        regK = Kg[(size_t)pjReg * NN + rn];
        regPC = PCT[(size_t)rn * MM + tid];
        regU = Uin[(size_t)(base + t + 1) * MM + tid];
      }
      const int j = tid & 127;
      const int bbg = tid >> 7;
      u64 pn0 = sPrevN[0], pn1 = sPrevN[1];
      u64 cs0 = sCurS[0], cs1 = sCurS[1];
      int nBj = (int)(((j < 64 ? pn0 : pn1) >> (j & 63)) & 1);
      int oBj = (int)(((j < 64 ? cs0 : cs1) >> (j & 63)) & 1);
      int sh = (bbg * 16) & 63;
      unsigned rowN = (unsigned)(((bbg < 4 ? pn0 : pn1) >> sh) & 0xFFFFull);
      unsigned rowO = (unsigned)(((bbg < 4 ? cs0 : cs1) >> sh) & 0xFFFFull);
      int q = sSt1[j];
      int pk[16];
      {
        const int4* p4 = (const int4*)(&sSt1[bbg * 16]);
        int4 a = p4[0], b = p4[1], c = p4[2], d = p4[3];
        pk[0]=a.x; pk[1]=a.y; pk[2]=a.z; pk[3]=a.w;
        pk[4]=b.x; pk[5]=b.y; pk[6]=b.z; pk[7]=b.w;
        pk[8]=c.x; pk[9]=c.y; pk[10]=c.z; pk[11]=c.w;
        pk[12]=d.x; pk[13]=d.y; pk[14]=d.z; pk[15]=d.w;
      }
      float kc[16];
      {
        const float4* k4 = (const float4*)(&sKc[bbg * 16]);
        float4 a = k4[0], b = k4[1], c = k4[2], d = k4[3];
        kc[0]=a.x; kc[1]=a.y; kc[2]=a.z; kc[3]=a.w;
        kc[4]=b.x; kc[5]=b.y; kc[6]=b.z; kc[7]=b.w;
        kc[8]=c.x; kc[9]=c.y; kc[10]=c.z; kc[11]=c.w;
        kc[12]=d.x; kc[13]=d.y; kc[14]=d.z; kc[15]=d.w;
      }
      int dwv[4];
      {
        const int* dT = (const int*)sDT;
        int di = j * 33 + bbg * 4;
        dwv[0] = dT[di]; dwv[1] = dT[di + 1]; dwv[2] = dT[di + 2]; dwv[3] = dT[di + 3];
      }
      int myP1 = 0, myRR = 0, myr = 0, myQ = 0;
      double myC = 0.0;
#pragma unroll
      for (int k = 0; k < 16; ++k) {
        int bb = bbg * 16 + k;
        int idx = bb * PAD + j;
        int x = sStS[idx];
        int nA = (int)((rowN >> k) & 1), oA = (int)((rowO >> k) & 1);
        if (nA | oA) {
          int dlt = (nA & nBj) - (oA & oBj);
          if (dlt) { x += dlt; sStS[idx] = x; }
        }
        int p = pk[k];
        int y = x + x, pq = p + q;
        int t2 = pq + q - 4095, t3 = pq + p - 4095;
        int b2 = (q < y) & (q < p) & (y > t2);
        int b4 = (pq > 4095) & (y < t2) & (y < t3);
        myr += b2 - b4;
        if (oA) {  // s-bit of row bb (wave-uniform)
          int b1 = (y < q) & (y < p) & (pq < 4095);
          int b3 = (p < y) & (p < q) & (y > t3);
          myRR += b1 - b2 - b3 + b4;
          myP1 += x;
        }
        myQ += x * p;
        int cdv = (int)((signed char)((dwv[k >> 2] >> ((k & 3) * 8)) & 0xFF));
        myC += (double)cdv * (double)kc[k];
      }
      int o = bbg * 128 + j;
      rP1[o] = myP1; rRR[o] = myRR; rr_[o] = myr; rQ[o] = myQ; rC[o] = myC;
    }
    __syncthreads();

    // ---- reduce (fixed order, deterministic)
    if (tid < 128) {
      long long Q = 0; int P1 = 0, RR = 0, r = 0; double C = 0.0;
#pragma unroll
      for (int g = 0; g < 8; ++g) {
        int o = g * 128 + tid;
        Q += (long long)rQ[o]; P1 += rP1[o]; RR += rRR[o]; r += rr_[o]; C += rC[o];
      }
      sQd[tid] = (double)Q; sP1[tid] = P1; sRRi[tid] = RR; sRv[tid] = r; sCorr[tid] = C;
    }
    __syncthreads();

    // ---- B: wave0 sequential element loop
    if (tid < 64) {
      const int l = tid;
      int st0i = sSt1[l], st1i = sSt1[l + 64];
      double st0d = (double)st0i, st1d = (double)st1i;
      int rv0 = sRv[l], rv1 = sRv[l + 64];
      double Q0 = sQd[l], Q1 = sQd[l + 64];
      int P1i0 = sP1[l], P1i1 = sP1[l + 64];
      int RRi0 = sRRi[l], RRi1 = sRRi[l + 64];
      u64 um0 = sCurS[0], um1 = sCurS[1];
      int sb0 = (int)((um0 >> l) & 1), sb1 = (int)((um1 >> l) & 1);
      int nb0 = sb0, nb1 = sb1;
      double k0d = (double)sKc[t];
      double Sk0 = sPC[l] + sCorr[l] - (sb0 ? k0d : 0.0);
      double Sk1 = sPC[l + 64] + sCorr[l + 64] - (sb1 ? k0d : 0.0);
      const double cc = 4095.0;
      const double tt = 4095.0 / 4096.0;
      double s_0 = st0d / cc, s_1 = st1d / cc;
      double uv0 = 2.0 * s_0 - 1.0, uv1 = 2.0 * s_1 - 1.0;
      double ssc0 = s_0 * (1.0 - s_0), ssc1 = s_1 * (1.0 - s_1);
      double Jii0 = 2.0 * cc * ssc0 + tt * uv0 * uv0;
      double Jii1 = 2.0 * cc * ssc1 + tt * uv1 * uv1;
      double sscS = ssc0 + ssc1;
      double SSv = st0d * st0d + st1d * st1d;
      double S1v = st0d + st1d;
      int SNi = st0i * nb0 + st1i * nb1;
      int Nni = nb0 + nb1;
#pragma unroll
      for (int o = 1; o < 64; o <<= 1) {
        sscS += __shfl_xor(sscS, o);
        SSv += __shfl_xor(SSv, o);
        S1v += __shfl_xor(S1v, o);
        SNi += __shfl_xor(SNi, o);
        Nni += __shfl_xor(Nni, o);
      }
      double h0 = tt * (sscS - k0d) * uv0 + 2.0 * Sk0 - 0.01 * (double)rv0;
      double h1 = tt * (sscS - k0d) * uv1 + 2.0 * Sk1 - 0.01 * (double)rv1;
      double c2 = cc * cc;
      double SSc2 = SSv / c2, S1sc = S1v / cc;
      double C00 = 2.0 * h0 - Jii0 + 4.0 * Q0 / cc + 4.0 * SSc2 * (tt * uv0 - st0d) - 2.0 * tt * uv0 * S1sc;
      double C01 = 2.0 * h1 - Jii1 + 4.0 * Q1 / cc + 4.0 * SSc2 * (tt * uv1 - st1d) - 2.0 * tt * uv1 * S1sc;
      double C10 = (4.0 / cc) * (st0d - tt * uv0), C11 = (4.0 / cc) * (st1d - tt * uv1);
      double C20 = 2.0 * tt * uv0, C21 = 2.0 * tt * uv1;
      double JT0 = 2.0 * Jii0, JT1 = 2.0 * Jii1;
      float uu0 = sU[l], uu1 = sU[l + 64];
      double L0 = (uu0 <= 0.0f) ? -1e300 : log((double)uu0 / (1.0 - (double)uu0));
      double L1 = (uu1 <= 0.0f) ? -1e300 : log((double)uu1 / (1.0 - (double)uu1));
      double E0 = C00 + C10 * (double)SNi + C20 * (double)Nni + (nb0 ? JT0 : 0.0);
      double E1 = C01 + C11 * (double)SNi + C21 * (double)Nni + (nb1 ? JT1 : 0.0);
      u64 nm0 = __ballot(nb0 != 0), nm1 = __ballot(nb1 != 0);
      int jmin = 0;
      while (jmin < 128) {
        double cur0 = E0 - 4.0 * (double)P1i0 - 0.02 * (double)RRi0;
        double cur1 = E1 - 4.0 * (double)P1i1 - 0.02 * (double)RRi1;
        int d0 = (cur0 < -100.0) ? 0 : ((cur0 > 100.0) ? 1 : (L0 < cur0 ? 1 : 0));
        int d1 = (cur1 < -100.0) ? 0 : ((cur1 > 100.0) ? 1 : (L1 < cur1 ? 1 : 0));
        u64 f0 = __ballot(d0 != nb0);
        u64 f1 = __ballot(d1 != nb1);
        if (jmin < 64) {
          f0 &= (~0ull) << jmin;
        } else {
          f0 = 0;
          f1 &= (~0ull) << (jmin - 64);
        }
        if (!(f0 | f1)) break;
        int jj = f0 ? __builtin_ctzll(f0) : 64 + __builtin_ctzll(f1);
        int slot = jj >> 6, ll = jj & 63;
        int nbjj = (int)(((slot ? nm1 : nm0) >> ll) & 1);
        int dsi = 1 - 2 * nbjj;
        int stjj = __shfl(slot ? st1i : st0i, ll);
        int x0 = sStS[jj * PAD + l];
        int x1 = sStS[jj * PAD + 64 + l];
        // E update hides under LDS latency
        double dsd = (double)dsi;
        double dst = dsd * (double)stjj;
        E0 += C10 * dst + C20 * dsd;
        E1 += C11 * dst + C21 * dsd;
        if (slot == 0 && l == ll) E0 += dsd * JT0;
        if (slot == 1 && l == ll) E1 += dsd * JT1;
        int p = stjj;
        int R0, R1;
        {
          int y = x0 + x0, pq = p + st0i, t2 = pq + st0i - 4095, t3 = pq + p - 4095;
          int b1 = (y < st0i) & (y < p) & (pq < 4095);
          int b2 = (st0i < y) & (st0i < p) & (y > t2);
          int b3 = (p < y) & (p < st0i) & (y > t3);
          int b4 = (pq > 4095) & (y < t2) & (y < t3);
          R0 = b1 - b2 - b3 + b4;
        }
        {
          int y = x1 + x1, pq = p + st1i, t2 = pq + st1i - 4095, t3 = pq + p - 4095;
          int b1 = (y < st1i) & (y < p) & (pq < 4095);
          int b2 = (st1i < y) & (st1i < p) & (y > t2);
          int b3 = (p < y) & (p < st1i) & (y > t3);
          int b4 = (pq > 4095) & (y < t2) & (y < t3);
          R1 = b1 - b2 - b3 + b4;
        }
        if (dsi > 0) { P1i0 += x0; P1i1 += x1; RRi0 += R0; RRi1 += R1; }
        else         { P1i0 -= x0; P1i1 -= x1; RRi0 -= R0; RRi1 -= R1; }
        if (slot == 0) { nm0 ^= (1ull << ll); if (l == ll) nb0 ^= 1; }
        else           { nm1 ^= (1ull << ll); if (l == ll) nb1 ^= 1; }
        jmin = jj + 1;
      }
      // commit
      int row = sPerm[t];
      signed char dd0 = (signed char)(nb0 - sb0);
      signed char dd1 = (signed char)(nb1 - sb1);
      sDT[l * PAD + t] = dd0;
      sDT[(l + 64) * PAD + t] = dd1;
      Dg[(size_t)(base + t) * MM + l] = dd0;
      Dg[(size_t)(base + t) * MM + 64 + l] = dd1;
      if (l == 0) {
        sPrevN[0] = nm0; sPrevN[1] = nm1;
        RMg[(size_t)row * 2] = nm0;
        RMg[(size_t)row * 2 + 1] = nm1;
      }
    }
    __syncthreads();
  }

  // ---- epilogue: stream out with news_127 applied
  u64 fn0 = sPrevN[0], fn1 = sPrevN[1];
  for (int k = 0; k < 16; ++k) {
    int idx = k * 1024 + tid;
    int a = idx >> 7, b = idx & 127;
    int na = (int)(((a < 64 ? fn0 : fn1) >> (a & 63)) & 1);
    int nb = (int)(((b < 64 ? fn0 : fn1) >> (b & 63)) & 1);
    StSg[idx] = sStS[a * PAD + b] + (na & nb);
  }
  if (tid < 128) {
    int nb = (int)((((tid < 64) ? fn0 : fn1) >> (tid & 63)) & 1);
    St1g[tid] = sSt1[tid] + nb;
  }
}

// ---------------- output: out = Snew @ Snew^T via popcount ----------------
__global__ void k_copy_tail(char* scratch, float* out) {
  u64* TM = (u64*)((char*)out + TAILB);
  const u64* RM = (const u64*)(scratch + OFF_RM);
  int tid = threadIdx.x;
  for (int k = 0; k < 16; ++k) TM[k * 512 + tid] = RM[k * 512 + tid];
}

__global__ void k_out_main(float* __restrict__ out) {
  const u64* TM = (const u64*)((const char*)out + TAILB);
  int a = blockIdx.x;  // 0..4091
  u64 a0 = TM[a * 2], a1 = TM[a * 2 + 1];
  int tid = threadIdx.x;
  for (int k = 0; k < 16; ++k) {
    int b = k * 256 + tid;
    u64 b0 = TM[b * 2], b1 = TM[b * 2 + 1];
    out[(size_t)a * NN + b] = (float)(__popcll(a0 & b0) + __popcll(a1 & b1));
  }
}

__global__ void k_out_tail(float* __restrict__ out) {
  __shared__ u64 sM[8192];
  const u64* TM = (const u64*)((const char*)out + TAILB);
  int tid = threadIdx.x;
  for (int k = 0; k < 8; ++k) sM[k * 1024 + tid] = TM[k * 1024 + tid];
  __syncthreads();
  for (int k = 0; k < 16; ++k) {
    int e = k * 1024 + tid;
    int a = 4092 + (e >> 12), b = e & 4095;
    out[(size_t)a * NN + b] =
        (float)(__popcll(sM[a * 2] & sM[b * 2]) + __popcll(sM[a * 2 + 1] & sM[b * 2 + 1]));
  }
}

extern "C" void kernel_launch(void* const* d_in, const int* in_sizes, int n_in,
                              void* d_out, int out_size, void* d_ws, size_t ws_size,
                              hipStream_t stream) {
  (void)in_sizes; (void)n_in; (void)out_size; (void)d_ws; (void)ws_size;
  const float* K = (const float*)d_in[0];
  const float* S = (const float*)d_in[1];
  const float* U = (const float*)d_in[2];
  const int* perm = (const int*)d_in[3];
  char* scratch = (char*)d_out;
  float* out = (float*)d_out;
  u64* RM = (u64*)(scratch + OFF_RM);
  u64* CM = (u64*)(scratch + OFF_CM);
  int* StSg = (int*)(scratch + OFF_STS);
  int* St1g = (int*)(scratch + OFF_ST1);
  double* PCT = (double*)(scratch + OFF_PCT);
  signed char* Dg = (signed char*)(scratch + OFF_D);

  hipLaunchKernelGGL(k_pack_rows, dim3(64), dim3(256), 0, stream, S, RM);
  hipLaunchKernelGGL(k_pack_cols, dim3(32), dim3(256), 0, stream, S, CM);
  hipLaunchKernelGGL(k_init_sts, dim3(64), dim3(256), 0, stream, CM, StSg, St1g);
  hipLaunchKernelGGL(k_pgemm, dim3(256), dim3(256), 0, stream, K, S, PCT);
  for (int b = 0; b < 32; ++b) {
    hipLaunchKernelGGL(k_seq, dim3(1), dim3(1024), 0, stream, K, U, perm, scratch, b);
    if (b < 31)
      hipLaunchKernelGGL(k_cgemm, dim3(256), dim3(256), 0, stream, K, perm, Dg, PCT, b);
  }
  hipLaunchKernelGGL(k_copy_tail, dim3(1), dim3(512), 0, stream, scratch, out);
  hipLaunchKernelGGL(k_out_main, dim3(4092), dim3(256), 0, stream, out);
  hipLaunchKernelGGL(k_out_tail, dim3(1), dim3(1024), 0, stream, out);
}